// Round 16
// baseline (265.043 us; speedup 1.0000x reference)
//
#include <hip/hip_runtime.h>

// GCN 3-layer on MI355X. R16 = R11 (best, 179.5us) + ONE change:
// hipMemcpyAsync x -> xc (d_ws) first, gemm1 reads xc. Probes whether the
// ~1.75 TB/s x-read wall is d_in-buffer-specific (copy engine fast -> win)
// or path-level (copy also ~117us -> we are at the roofline).
// 7 nodes: memcpy -> init -> [scatter||gemm1] -> build -> g1 -> g2 -> g3.

typedef __bf16 bf16x8 __attribute__((ext_vector_type(8)));
typedef short short8v __attribute__((ext_vector_type(8)));
typedef unsigned short ushort8v __attribute__((ext_vector_type(8)));
typedef unsigned short ushort4v __attribute__((ext_vector_type(4)));
typedef float float4v __attribute__((ext_vector_type(4)));

static inline int ceil_div_i(long long a, long long b) { return (int)((a + b - 1) / b); }

#define CAP 16384      // per-bucket arena capacity
#define SCHUNK 8192    // edges per scatter block (196 blocks)
#define RPB 128        // gemm1 rows per block

#define GLOAD_LDS16(gsrc, ldst)                                                  \
    __builtin_amdgcn_global_load_lds(                                            \
        (const __attribute__((address_space(1))) unsigned*)(gsrc),               \
        (__attribute__((address_space(3))) unsigned*)(ldst), 16, 0, 0)

__device__ inline unsigned short bf16rne(float f) {
    union { float f; unsigned u; } c; c.f = f;
    unsigned u = c.u;
    u += 0x7fffu + ((u >> 16) & 1u);
    return (unsigned short)(u >> 16);
}
__device__ inline float bf16tof(unsigned short h) {
    return __uint_as_float((unsigned)h << 16);
}

// ---------------- D1: arena tails + W1 -> bf16 transposed [64][512] ----------------
__global__ __launch_bounds__(256) void init_kernel(const float* __restrict__ W1,
                                                   unsigned short* __restrict__ wt,
                                                   int* __restrict__ gtail) {
    const int t = threadIdx.x;
    if (blockIdx.x == 0) gtail[t] = t * CAP;
    for (int i = blockIdx.x * 256 + t; i < 512 * 64; i += gridDim.x * 256) {
        int k = i >> 6, n = i & 63;
        wt[(size_t)n * 512 + k] = bf16rne(W1[i]);
    }
}

// ---------------- D2: FAT — arena scatter || LDS-staged GEMM1 MFMA ----------------
__global__ __launch_bounds__(256) void scatter_gemm1_kernel(
        const int* __restrict__ src, const int* __restrict__ dst,
        int* __restrict__ gtail, unsigned* __restrict__ abuf, int E, int EB,
        const float* __restrict__ x, const unsigned short* __restrict__ wt,
        unsigned short* __restrict__ g1, int M) {
    __shared__ int cur[256];
    __shared__ __align__(16) char xs[RPB * 32 * 4];           // 16 KB swizzled x tile
    __shared__ __align__(16) unsigned short wst[64 * 40];     // 5 KB padded wt chunk
    const int t = threadIdx.x;
    if (blockIdx.x < EB) {
        // ---- scatter path ----
        const int e0 = blockIdx.x * SCHUNK;
        const int e1 = min(e0 + SCHUNK, E);
        cur[t] = 0;
        __syncthreads();
        for (int e = e0 + t; e < e1; e += 256) atomicAdd(&cur[dst[e] >> 9], 1);
        __syncthreads();
        int c = cur[t];
        cur[t] = c ? atomicAdd(&gtail[t], c) : 0;
        __syncthreads();
        for (int e = e0 + t; e < e1; e += 256) {
            int d = dst[e];
            int pos = atomicAdd(&cur[d >> 9], 1);
            abuf[pos] = ((unsigned)(d & 511) << 23) | (unsigned)src[e];
        }
        return;
    }
    // ---- gemm1 path (LDS-staged) ----
    const int tile = blockIdx.x - EB;
    const int w = t >> 6, l = t & 63;
    const int lr = l & 15, g = l >> 4;
    const int row0 = tile * RPB;
    float4v acc[2][4] = {};

    for (int c = 0; c < 16; ++c) {
        const int k0 = c * 32;
        if (c) __syncthreads();
        {   // stage x tile [128][32] f32, swizzled (byte ^= (row&7)<<4)
            char* ldsb = xs + w * 4096;
            #pragma unroll
            for (int j = 0; j < 4; ++j) {
                int o = w * 4096 + j * 1024 + l * 16;
                int r = o >> 7;
                int colb = (o & 127) ^ ((r & 7) << 4);
                int grow = row0 + r;
                if (grow >= M) grow = 0;
                const char* gs = (const char*)x + (size_t)grow * 2048 +
                                 (size_t)k0 * 4 + colb;
                GLOAD_LDS16(gs, ldsb + j * 1024);
            }
        }
        {   // stage wt chunk [64][32] bf16 -> padded [64][40]
            int n = t >> 2, q = t & 3;
            ushort8v v = *(const ushort8v*)(wt + (size_t)n * 512 + k0 + q * 8);
            *(ushort8v*)&wst[n * 40 + q * 8] = v;
        }
        __syncthreads();
        bf16x8 bf[4];
        #pragma unroll
        for (int f = 0; f < 4; ++f)
            bf[f] = *(const bf16x8*)&wst[(f * 16 + lr) * 40 + g * 8];
        #pragma unroll
        for (int st = 0; st < 2; ++st) {
            const int r = w * 32 + st * 16 + lr;
            const int swz = (r & 7) << 4;
            const char* base = xs + r * 128;
            float4 xa = *(const float4*)(base + ((g * 32) ^ swz));
            float4 xb = *(const float4*)(base + ((g * 32 + 16) ^ swz));
            short8v av;
            av[0] = (short)bf16rne(xa.x); av[1] = (short)bf16rne(xa.y);
            av[2] = (short)bf16rne(xa.z); av[3] = (short)bf16rne(xa.w);
            av[4] = (short)bf16rne(xb.x); av[5] = (short)bf16rne(xb.y);
            av[6] = (short)bf16rne(xb.z); av[7] = (short)bf16rne(xb.w);
            bf16x8 a = __builtin_bit_cast(bf16x8, av);
            #pragma unroll
            for (int f = 0; f < 4; ++f)
                acc[st][f] = __builtin_amdgcn_mfma_f32_16x16x32_bf16(a, bf[f],
                                                                     acc[st][f], 0, 0, 0);
        }
    }
    #pragma unroll
    for (int st = 0; st < 2; ++st) {
        const int ro0 = row0 + w * 32 + st * 16 + 4 * g;
        #pragma unroll
        for (int r = 0; r < 4; ++r) {
            int ro = ro0 + r;
            if (ro < M) {
                #pragma unroll
                for (int f = 0; f < 4; ++f)
                    g1[(size_t)ro * 64 + f * 16 + lr] = bf16rne(acc[st][f][r]);
            }
        }
    }
}

// ---------------- D3: per-bucket hist+scan -> row_start/row_end/dis, place csr ----------------
__global__ __launch_bounds__(256) void build_kernel(const int* __restrict__ gtail,
                                                    const unsigned* __restrict__ abuf,
                                                    int* __restrict__ row_start,
                                                    int* __restrict__ row_end,
                                                    float* __restrict__ dis,
                                                    int* __restrict__ csr_src, int M) {
    __shared__ int hist[512];
    __shared__ int cur[512];
    __shared__ int wsum_[4];
    const int b = blockIdx.x, t = threadIdx.x, lane = t & 63, wid = t >> 6;
    const int n0 = b << 9;
    const int s = b * CAP;
    const int e = gtail[b];
    hist[t] = 0; hist[t + 256] = 0;
    __syncthreads();
    for (int i = s + t; i < e; i += 256) atomicAdd(&hist[abuf[i] >> 23], 1);
    __syncthreads();
    int c0 = hist[2 * t], c1 = hist[2 * t + 1];
    int pair = c0 + c1;
    int inc = pair;
    #pragma unroll
    for (int d = 1; d < 64; d <<= 1) {
        int o = __shfl_up(inc, d);
        if (lane >= d) inc += o;
    }
    if (lane == 63) wsum_[wid] = inc;
    __syncthreads();
    int wpre = 0;
    for (int ww = 0; ww < wid; ++ww) wpre += wsum_[ww];
    int excl = wpre + inc - pair;
    int r0 = s + excl, r1 = r0 + c0;
    int n = n0 + 2 * t;
    if (n < M) {
        row_start[n] = r0; row_end[n] = r1;
        dis[n] = rsqrtf((float)(c0 + 1));
    }
    if (n + 1 < M) {
        row_start[n + 1] = r1; row_end[n + 1] = r1 + c1;
        dis[n + 1] = rsqrtf((float)(c1 + 1));
    }
    cur[2 * t] = r0; cur[2 * t + 1] = r1;
    __syncthreads();
    for (int i = s + t; i < e; i += 256) {
        unsigned p = abuf[i];
        int pos = atomicAdd(&cur[p >> 23], 1);
        csr_src[pos] = (int)(p & 0x7fffffu);
    }
}

// ---------------- D4-D6: gather + fused MLP ----------------
template <int F, int FOUT, int LPN, bool RELU, bool FINAL, bool EDGEW>
__global__ __launch_bounds__(256) void gather_mlp_kernel(
        const int* __restrict__ row_start, const int* __restrict__ row_end,
        const int* __restrict__ csr_src, const float* __restrict__ dis,
        const unsigned short* __restrict__ gin, const float* __restrict__ bin,
        const float* __restrict__ W, const float* __restrict__ bout,
        void* __restrict__ o_, int M) {
    constexpr int VEC = F / LPN;
    constexpr int NPB = 256 / LPN;
    constexpr int HSS = F + 4;
    __shared__ float Ws[F * FOUT];
    __shared__ float hs[NPB][HSS];
    __shared__ float bs[FINAL ? FOUT : 1];
    const int t = threadIdx.x;
    for (int i = t; i < F * FOUT; i += 256) Ws[i] = W[i];
    if (FINAL && t < FOUT) bs[t] = bout[t];
    const int grp = t / LPN, gl = t % LPN;
    const int n = blockIdx.x * NPB + grp;
    float dn = 0.f;
    if (n < M) {
        const int rs = row_start[n], re = row_end[n];
        dn = dis[n];
        float acc[VEC] = {};
        int i = rs;
        while (i < re) {
            const int take = re - i;
            int s = 0; float wl = 0.f;
            if (gl < take) {
                s = csr_src[i + gl];
                if constexpr (EDGEW) wl = dis[s];
            }
            #pragma unroll
            for (int jj = 0; jj < LPN; ++jj) {
                if (jj < take) {
                    int sj = __shfl(s, jj, LPN);
                    float wj;
                    if constexpr (EDGEW) wj = __shfl(wl, jj, LPN) * dn;
                    if constexpr (VEC == 8) {
                        ushort8v r8 = *(const ushort8v*)(gin + (size_t)sj * F + gl * 8);
                        #pragma unroll
                        for (int k = 0; k < 8; ++k) {
                            float v = bf16tof(r8[k]);
                            if constexpr (EDGEW) acc[k] += wj * v; else acc[k] += v;
                        }
                    } else {
                        ushort4v r4 = *(const ushort4v*)(gin + (size_t)sj * F + gl * 4);
                        #pragma unroll
                        for (int k = 0; k < 4; ++k) {
                            float v = bf16tof(r4[k]);
                            if constexpr (EDGEW) acc[k] += wj * v; else acc[k] += v;
                        }
                    }
                }
            }
            i += LPN;
        }
        const float sw = EDGEW ? dn * dn : 1.f;
        if constexpr (VEC == 8) {
            ushort8v r8 = *(const ushort8v*)(gin + (size_t)n * F + gl * 8);
            #pragma unroll
            for (int k = 0; k < 8; ++k) acc[k] += sw * bf16tof(r8[k]);
        } else {
            ushort4v r4 = *(const ushort4v*)(gin + (size_t)n * F + gl * 4);
            #pragma unroll
            for (int k = 0; k < 4; ++k) acc[k] += sw * bf16tof(r4[k]);
        }
        #pragma unroll
        for (int k = 0; k < VEC; ++k) {
            float pre = EDGEW ? acc[k] : dn * acc[k];
            float r = pre + bin[gl * VEC + k];
            if (RELU) r = fmaxf(r, 0.f);
            hs[grp][gl * VEC + k] = r;
        }
    }
    __syncthreads();
    if (!FINAL) {
        constexpr int OCPT = FOUT / LPN;
        if (n < M) {
            const int oc0 = gl * OCPT;
            float a[OCPT] = {};
            #pragma unroll
            for (int k = 0; k < F; ++k) {
                float hv = hs[grp][k];
                if constexpr (OCPT == 4) {
                    float4 wv = *(const float4*)&Ws[k * FOUT + oc0];
                    a[0] += hv * wv.x; a[1] += hv * wv.y;
                    a[2] += hv * wv.z; a[3] += hv * wv.w;
                } else {
                    float2 wv = *(const float2*)&Ws[k * FOUT + oc0];
                    a[0] += hv * wv.x; a[1] += hv * wv.y;
                }
            }
            unsigned short* o = (unsigned short*)o_;
            if constexpr (OCPT == 4) {
                ushort4v pk;
                #pragma unroll
                for (int j = 0; j < 4; ++j) pk[j] = bf16rne(a[j] * dn);
                *(ushort4v*)(o + (size_t)n * FOUT + oc0) = pk;
            } else {
                #pragma unroll
                for (int j = 0; j < OCPT; ++j)
                    o[(size_t)n * FOUT + oc0 + j] = bf16rne(a[j] * dn);
            }
        }
    } else {
        float* o = (float*)o_;
        for (int idx = t; idx < NPB * FOUT; idx += 256) {
            int nl = idx / FOUT, oc = idx % FOUT;
            int nn = blockIdx.x * NPB + nl;
            if (nn >= M) continue;
            float a = bs[oc];
            #pragma unroll
            for (int k = 0; k < F; ++k) a += hs[nl][k] * Ws[k * FOUT + oc];
            o[(size_t)nn * FOUT + oc] = a;
        }
    }
}

extern "C" void kernel_launch(void* const* d_in, const int* in_sizes, int n_in,
                              void* d_out, int out_size, void* d_ws, size_t ws_size,
                              hipStream_t stream) {
    const float* x  = (const float*)d_in[0];
    const int* eidx = (const int*)d_in[1];
    const float* W1 = (const float*)d_in[2];
    const float* b1 = (const float*)d_in[3];
    const float* W2 = (const float*)d_in[4];
    const float* b2 = (const float*)d_in[5];
    const float* W3 = (const float*)d_in[6];
    const float* b3 = (const float*)d_in[7];
    const float* Wl = (const float*)d_in[8];
    const float* bl = (const float*)d_in[9];
    float* out = (float*)d_out;

    const int M = in_sizes[0] / 512;
    const int E = in_sizes[1] / 2;
    const int* src = eidx;
    const int* dst = eidx + E;
    const int NB = ceil_div_i(M, 512);
    const int EB = ceil_div_i(E, SCHUNK);   // 196
    const int NT = ceil_div_i(M, RPB);      // 782 gemm tiles

    // workspace
    char* ws = (char*)d_ws;
    const size_t szM1 = ((size_t)(M + 1) * 4 + 255) & ~(size_t)255;
    const size_t szAR = ((size_t)NB * CAP * 4 + 255) & ~(size_t)255;
    size_t off = 0;
    int*      gtail     = (int*)(ws + off); off += 1024;
    int*      row_start = (int*)(ws + off); off += szM1;
    int*      row_end   = (int*)(ws + off); off += szM1;
    float*    dis       = (float*)(ws + off); off += szM1;
    unsigned* abuf      = (unsigned*)(ws + off); off += szAR;
    int*      csr_src   = (int*)(ws + off); off += szAR;
    unsigned short* wt  = (unsigned short*)(ws + off); off += 66560;
    unsigned short* g1  = (unsigned short*)(ws + off);
    off += ((size_t)M * 64 * 2 + 255) & ~(size_t)255;
    unsigned short* g2  = (unsigned short*)(ws + off);
    off += ((size_t)M * 32 * 2 + 255) & ~(size_t)255;
    unsigned short* g3  = (unsigned short*)(ws + off);
    off += ((size_t)M * 16 * 2 + 255) & ~(size_t)255;
    off = (off + 255) & ~(size_t)255;
    const size_t xcBytes = (size_t)M * 512 * sizeof(float);  // 204.8 MB
    float* xc = (float*)(ws + off);
    const bool useCopy = (off + xcBytes) <= ws_size;
    const float* xeff = useCopy ? xc : x;

    // D0: PROBE — copy x to workspace via the memcpy engine
    if (useCopy)
        hipMemcpyAsync(xc, x, xcBytes, hipMemcpyDeviceToDevice, stream);

    // D1: init (gtail + W1^T)
    init_kernel<<<128, 256, 0, stream>>>(W1, wt, gtail);
    // D2: scatter || gemm1 (gemm reads xc)
    scatter_gemm1_kernel<<<EB + NT, 256, 0, stream>>>(src, dst, gtail, abuf, E, EB,
                                                      xeff, wt, g1, M);
    // D3: build CSR + dis
    build_kernel<<<NB, 256, 0, stream>>>(gtail, abuf, row_start, row_end, dis, csr_src, M);

    // D4: layer 1 (edge-weighted)
    gather_mlp_kernel<64, 32, 8, true, false, true><<<ceil_div_i(M, 32), 256, 0, stream>>>(
        row_start, row_end, csr_src, dis, g1, b1, W2, nullptr, g2, M);
    // D5: layer 2 (weight-free)
    gather_mlp_kernel<32, 16, 8, true, false, false><<<ceil_div_i(M, 32), 256, 0, stream>>>(
        row_start, row_end, csr_src, dis, g2, b2, W3, nullptr, g3, M);
    // D6: layer 3 + final linear (weight-free, f32 out)
    gather_mlp_kernel<16, 7, 4, false, true, false><<<ceil_div_i(M, 64), 256, 0, stream>>>(
        row_start, row_end, csr_src, dis, g3, b3, Wl, bl, out, M);
}

// Round 17
// 180.436 us; speedup vs baseline: 1.4689x; 1.4689x over previous
//
#include <hip/hip_runtime.h>

// GCN 3-layer on MI355X. R17 = exact revert to R11 (best: 179.5us).
// R16's memcpy probe established the ~1.75-2.4 TB/s large-read wall is
// path-level (any reader, incl. SDMA); x-read (205MB) = ~117us structural.
// R11 = that wall (scatter fused inside it) + cache-speed dependent tail.
// 6 dispatches: init -> [scatter||gemm1] -> build -> g1 -> g2 -> g3.

typedef __bf16 bf16x8 __attribute__((ext_vector_type(8)));
typedef short short8v __attribute__((ext_vector_type(8)));
typedef unsigned short ushort8v __attribute__((ext_vector_type(8)));
typedef unsigned short ushort4v __attribute__((ext_vector_type(4)));
typedef float float4v __attribute__((ext_vector_type(4)));

static inline int ceil_div_i(long long a, long long b) { return (int)((a + b - 1) / b); }

#define CAP 16384      // per-bucket arena capacity
#define SCHUNK 8192    // edges per scatter block (196 blocks)
#define RPB 128        // gemm1 rows per block

#define GLOAD_LDS16(gsrc, ldst)                                                  \
    __builtin_amdgcn_global_load_lds(                                            \
        (const __attribute__((address_space(1))) unsigned*)(gsrc),               \
        (__attribute__((address_space(3))) unsigned*)(ldst), 16, 0, 0)

__device__ inline unsigned short bf16rne(float f) {
    union { float f; unsigned u; } c; c.f = f;
    unsigned u = c.u;
    u += 0x7fffu + ((u >> 16) & 1u);
    return (unsigned short)(u >> 16);
}
__device__ inline float bf16tof(unsigned short h) {
    return __uint_as_float((unsigned)h << 16);
}

// ---------------- D1: arena tails + W1 -> bf16 transposed [64][512] ----------------
__global__ __launch_bounds__(256) void init_kernel(const float* __restrict__ W1,
                                                   unsigned short* __restrict__ wt,
                                                   int* __restrict__ gtail) {
    const int t = threadIdx.x;
    if (blockIdx.x == 0) gtail[t] = t * CAP;
    for (int i = blockIdx.x * 256 + t; i < 512 * 64; i += gridDim.x * 256) {
        int k = i >> 6, n = i & 63;
        wt[(size_t)n * 512 + k] = bf16rne(W1[i]);
    }
}

// ---------------- D2: FAT — arena scatter || LDS-staged GEMM1 MFMA ----------------
__global__ __launch_bounds__(256) void scatter_gemm1_kernel(
        const int* __restrict__ src, const int* __restrict__ dst,
        int* __restrict__ gtail, unsigned* __restrict__ abuf, int E, int EB,
        const float* __restrict__ x, const unsigned short* __restrict__ wt,
        unsigned short* __restrict__ g1, int M) {
    __shared__ int cur[256];
    __shared__ __align__(16) char xs[RPB * 32 * 4];           // 16 KB swizzled x tile
    __shared__ __align__(16) unsigned short wst[64 * 40];     // 5 KB padded wt chunk
    const int t = threadIdx.x;
    if (blockIdx.x < EB) {
        // ---- scatter path ----
        const int e0 = blockIdx.x * SCHUNK;
        const int e1 = min(e0 + SCHUNK, E);
        cur[t] = 0;
        __syncthreads();
        for (int e = e0 + t; e < e1; e += 256) atomicAdd(&cur[dst[e] >> 9], 1);
        __syncthreads();
        int c = cur[t];
        cur[t] = c ? atomicAdd(&gtail[t], c) : 0;
        __syncthreads();
        for (int e = e0 + t; e < e1; e += 256) {
            int d = dst[e];
            int pos = atomicAdd(&cur[d >> 9], 1);
            abuf[pos] = ((unsigned)(d & 511) << 23) | (unsigned)src[e];
        }
        return;
    }
    // ---- gemm1 path (LDS-staged) ----
    const int tile = blockIdx.x - EB;
    const int w = t >> 6, l = t & 63;
    const int lr = l & 15, g = l >> 4;
    const int row0 = tile * RPB;
    float4v acc[2][4] = {};

    for (int c = 0; c < 16; ++c) {
        const int k0 = c * 32;
        if (c) __syncthreads();
        {   // stage x tile [128][32] f32, swizzled (byte ^= (row&7)<<4)
            char* ldsb = xs + w * 4096;
            #pragma unroll
            for (int j = 0; j < 4; ++j) {
                int o = w * 4096 + j * 1024 + l * 16;
                int r = o >> 7;
                int colb = (o & 127) ^ ((r & 7) << 4);
                int grow = row0 + r;
                if (grow >= M) grow = 0;
                const char* gs = (const char*)x + (size_t)grow * 2048 +
                                 (size_t)k0 * 4 + colb;
                GLOAD_LDS16(gs, ldsb + j * 1024);
            }
        }
        {   // stage wt chunk [64][32] bf16 -> padded [64][40]
            int n = t >> 2, q = t & 3;
            ushort8v v = *(const ushort8v*)(wt + (size_t)n * 512 + k0 + q * 8);
            *(ushort8v*)&wst[n * 40 + q * 8] = v;
        }
        __syncthreads();
        bf16x8 bf[4];
        #pragma unroll
        for (int f = 0; f < 4; ++f)
            bf[f] = *(const bf16x8*)&wst[(f * 16 + lr) * 40 + g * 8];
        #pragma unroll
        for (int st = 0; st < 2; ++st) {
            const int r = w * 32 + st * 16 + lr;
            const int swz = (r & 7) << 4;
            const char* base = xs + r * 128;
            float4 xa = *(const float4*)(base + ((g * 32) ^ swz));
            float4 xb = *(const float4*)(base + ((g * 32 + 16) ^ swz));
            short8v av;
            av[0] = (short)bf16rne(xa.x); av[1] = (short)bf16rne(xa.y);
            av[2] = (short)bf16rne(xa.z); av[3] = (short)bf16rne(xa.w);
            av[4] = (short)bf16rne(xb.x); av[5] = (short)bf16rne(xb.y);
            av[6] = (short)bf16rne(xb.z); av[7] = (short)bf16rne(xb.w);
            bf16x8 a = __builtin_bit_cast(bf16x8, av);
            #pragma unroll
            for (int f = 0; f < 4; ++f)
                acc[st][f] = __builtin_amdgcn_mfma_f32_16x16x32_bf16(a, bf[f],
                                                                     acc[st][f], 0, 0, 0);
        }
    }
    #pragma unroll
    for (int st = 0; st < 2; ++st) {
        const int ro0 = row0 + w * 32 + st * 16 + 4 * g;
        #pragma unroll
        for (int r = 0; r < 4; ++r) {
            int ro = ro0 + r;
            if (ro < M) {
                #pragma unroll
                for (int f = 0; f < 4; ++f)
                    g1[(size_t)ro * 64 + f * 16 + lr] = bf16rne(acc[st][f][r]);
            }
        }
    }
}

// ---------------- D3: per-bucket hist+scan -> row_start/row_end/dis, place csr ----------------
__global__ __launch_bounds__(256) void build_kernel(const int* __restrict__ gtail,
                                                    const unsigned* __restrict__ abuf,
                                                    int* __restrict__ row_start,
                                                    int* __restrict__ row_end,
                                                    float* __restrict__ dis,
                                                    int* __restrict__ csr_src, int M) {
    __shared__ int hist[512];
    __shared__ int cur[512];
    __shared__ int wsum_[4];
    const int b = blockIdx.x, t = threadIdx.x, lane = t & 63, wid = t >> 6;
    const int n0 = b << 9;
    const int s = b * CAP;
    const int e = gtail[b];
    hist[t] = 0; hist[t + 256] = 0;
    __syncthreads();
    for (int i = s + t; i < e; i += 256) atomicAdd(&hist[abuf[i] >> 23], 1);
    __syncthreads();
    int c0 = hist[2 * t], c1 = hist[2 * t + 1];
    int pair = c0 + c1;
    int inc = pair;
    #pragma unroll
    for (int d = 1; d < 64; d <<= 1) {
        int o = __shfl_up(inc, d);
        if (lane >= d) inc += o;
    }
    if (lane == 63) wsum_[wid] = inc;
    __syncthreads();
    int wpre = 0;
    for (int ww = 0; ww < wid; ++ww) wpre += wsum_[ww];
    int excl = wpre + inc - pair;
    int r0 = s + excl, r1 = r0 + c0;
    int n = n0 + 2 * t;
    if (n < M) {
        row_start[n] = r0; row_end[n] = r1;
        dis[n] = rsqrtf((float)(c0 + 1));
    }
    if (n + 1 < M) {
        row_start[n + 1] = r1; row_end[n + 1] = r1 + c1;
        dis[n + 1] = rsqrtf((float)(c1 + 1));
    }
    cur[2 * t] = r0; cur[2 * t + 1] = r1;
    __syncthreads();
    for (int i = s + t; i < e; i += 256) {
        unsigned p = abuf[i];
        int pos = atomicAdd(&cur[p >> 23], 1);
        csr_src[pos] = (int)(p & 0x7fffffu);
    }
}

// ---------------- D4-D6: gather + fused MLP ----------------
template <int F, int FOUT, int LPN, bool RELU, bool FINAL, bool EDGEW>
__global__ __launch_bounds__(256) void gather_mlp_kernel(
        const int* __restrict__ row_start, const int* __restrict__ row_end,
        const int* __restrict__ csr_src, const float* __restrict__ dis,
        const unsigned short* __restrict__ gin, const float* __restrict__ bin,
        const float* __restrict__ W, const float* __restrict__ bout,
        void* __restrict__ o_, int M) {
    constexpr int VEC = F / LPN;
    constexpr int NPB = 256 / LPN;
    constexpr int HSS = F + 4;
    __shared__ float Ws[F * FOUT];
    __shared__ float hs[NPB][HSS];
    __shared__ float bs[FINAL ? FOUT : 1];
    const int t = threadIdx.x;
    for (int i = t; i < F * FOUT; i += 256) Ws[i] = W[i];
    if (FINAL && t < FOUT) bs[t] = bout[t];
    const int grp = t / LPN, gl = t % LPN;
    const int n = blockIdx.x * NPB + grp;
    float dn = 0.f;
    if (n < M) {
        const int rs = row_start[n], re = row_end[n];
        dn = dis[n];
        float acc[VEC] = {};
        int i = rs;
        while (i < re) {
            const int take = re - i;
            int s = 0; float wl = 0.f;
            if (gl < take) {
                s = csr_src[i + gl];
                if constexpr (EDGEW) wl = dis[s];
            }
            #pragma unroll
            for (int jj = 0; jj < LPN; ++jj) {
                if (jj < take) {
                    int sj = __shfl(s, jj, LPN);
                    float wj;
                    if constexpr (EDGEW) wj = __shfl(wl, jj, LPN) * dn;
                    if constexpr (VEC == 8) {
                        ushort8v r8 = *(const ushort8v*)(gin + (size_t)sj * F + gl * 8);
                        #pragma unroll
                        for (int k = 0; k < 8; ++k) {
                            float v = bf16tof(r8[k]);
                            if constexpr (EDGEW) acc[k] += wj * v; else acc[k] += v;
                        }
                    } else {
                        ushort4v r4 = *(const ushort4v*)(gin + (size_t)sj * F + gl * 4);
                        #pragma unroll
                        for (int k = 0; k < 4; ++k) {
                            float v = bf16tof(r4[k]);
                            if constexpr (EDGEW) acc[k] += wj * v; else acc[k] += v;
                        }
                    }
                }
            }
            i += LPN;
        }
        const float sw = EDGEW ? dn * dn : 1.f;
        if constexpr (VEC == 8) {
            ushort8v r8 = *(const ushort8v*)(gin + (size_t)n * F + gl * 8);
            #pragma unroll
            for (int k = 0; k < 8; ++k) acc[k] += sw * bf16tof(r8[k]);
        } else {
            ushort4v r4 = *(const ushort4v*)(gin + (size_t)n * F + gl * 4);
            #pragma unroll
            for (int k = 0; k < 4; ++k) acc[k] += sw * bf16tof(r4[k]);
        }
        #pragma unroll
        for (int k = 0; k < VEC; ++k) {
            float pre = EDGEW ? acc[k] : dn * acc[k];
            float r = pre + bin[gl * VEC + k];
            if (RELU) r = fmaxf(r, 0.f);
            hs[grp][gl * VEC + k] = r;
        }
    }
    __syncthreads();
    if (!FINAL) {
        constexpr int OCPT = FOUT / LPN;
        if (n < M) {
            const int oc0 = gl * OCPT;
            float a[OCPT] = {};
            #pragma unroll
            for (int k = 0; k < F; ++k) {
                float hv = hs[grp][k];
                if constexpr (OCPT == 4) {
                    float4 wv = *(const float4*)&Ws[k * FOUT + oc0];
                    a[0] += hv * wv.x; a[1] += hv * wv.y;
                    a[2] += hv * wv.z; a[3] += hv * wv.w;
                } else {
                    float2 wv = *(const float2*)&Ws[k * FOUT + oc0];
                    a[0] += hv * wv.x; a[1] += hv * wv.y;
                }
            }
            unsigned short* o = (unsigned short*)o_;
            if constexpr (OCPT == 4) {
                ushort4v pk;
                #pragma unroll
                for (int j = 0; j < 4; ++j) pk[j] = bf16rne(a[j] * dn);
                *(ushort4v*)(o + (size_t)n * FOUT + oc0) = pk;
            } else {
                #pragma unroll
                for (int j = 0; j < OCPT; ++j)
                    o[(size_t)n * FOUT + oc0 + j] = bf16rne(a[j] * dn);
            }
        }
    } else {
        float* o = (float*)o_;
        for (int idx = t; idx < NPB * FOUT; idx += 256) {
            int nl = idx / FOUT, oc = idx % FOUT;
            int nn = blockIdx.x * NPB + nl;
            if (nn >= M) continue;
            float a = bs[oc];
            #pragma unroll
            for (int k = 0; k < F; ++k) a += hs[nl][k] * Ws[k * FOUT + oc];
            o[(size_t)nn * FOUT + oc] = a;
        }
    }
}

extern "C" void kernel_launch(void* const* d_in, const int* in_sizes, int n_in,
                              void* d_out, int out_size, void* d_ws, size_t ws_size,
                              hipStream_t stream) {
    const float* x  = (const float*)d_in[0];
    const int* eidx = (const int*)d_in[1];
    const float* W1 = (const float*)d_in[2];
    const float* b1 = (const float*)d_in[3];
    const float* W2 = (const float*)d_in[4];
    const float* b2 = (const float*)d_in[5];
    const float* W3 = (const float*)d_in[6];
    const float* b3 = (const float*)d_in[7];
    const float* Wl = (const float*)d_in[8];
    const float* bl = (const float*)d_in[9];
    float* out = (float*)d_out;

    const int M = in_sizes[0] / 512;
    const int E = in_sizes[1] / 2;
    const int* src = eidx;
    const int* dst = eidx + E;
    const int NB = ceil_div_i(M, 512);
    const int EB = ceil_div_i(E, SCHUNK);   // 196
    const int NT = ceil_div_i(M, RPB);      // 782 gemm tiles

    // workspace (~49 MB)
    char* ws = (char*)d_ws;
    const size_t szM1 = ((size_t)(M + 1) * 4 + 255) & ~(size_t)255;
    const size_t szAR = ((size_t)NB * CAP * 4 + 255) & ~(size_t)255;
    size_t off = 0;
    int*      gtail     = (int*)(ws + off); off += 1024;
    int*      row_start = (int*)(ws + off); off += szM1;
    int*      row_end   = (int*)(ws + off); off += szM1;
    float*    dis       = (float*)(ws + off); off += szM1;
    unsigned* abuf      = (unsigned*)(ws + off); off += szAR;
    int*      csr_src   = (int*)(ws + off); off += szAR;
    unsigned short* wt  = (unsigned short*)(ws + off); off += 66560;
    unsigned short* g1  = (unsigned short*)(ws + off);
    off += ((size_t)M * 64 * 2 + 255) & ~(size_t)255;
    unsigned short* g2  = (unsigned short*)(ws + off);
    off += ((size_t)M * 32 * 2 + 255) & ~(size_t)255;
    unsigned short* g3  = (unsigned short*)(ws + off);
    off += ((size_t)M * 16 * 2 + 255) & ~(size_t)255;

    // D1: init (gtail + W1^T)
    init_kernel<<<128, 256, 0, stream>>>(W1, wt, gtail);
    // D2: scatter || gemm1
    scatter_gemm1_kernel<<<EB + NT, 256, 0, stream>>>(src, dst, gtail, abuf, E, EB,
                                                      x, wt, g1, M);
    // D3: build CSR + dis
    build_kernel<<<NB, 256, 0, stream>>>(gtail, abuf, row_start, row_end, dis, csr_src, M);

    // D4: layer 1 (edge-weighted)
    gather_mlp_kernel<64, 32, 8, true, false, true><<<ceil_div_i(M, 32), 256, 0, stream>>>(
        row_start, row_end, csr_src, dis, g1, b1, W2, nullptr, g2, M);
    // D5: layer 2 (weight-free)
    gather_mlp_kernel<32, 16, 8, true, false, false><<<ceil_div_i(M, 32), 256, 0, stream>>>(
        row_start, row_end, csr_src, dis, g2, b2, W3, nullptr, g3, M);
    // D6: layer 3 + final linear (weight-free, f32 out)
    gather_mlp_kernel<16, 7, 4, false, true, false><<<ceil_div_i(M, 64), 256, 0, stream>>>(
        row_start, row_end, csr_src, dis, g3, b3, Wl, bl, out, M);
}